// Round 6
// baseline (292.774 us; speedup 1.0000x reference)
//
#include <hip/hip_runtime.h>
#include <math.h>

#define DIM 64
#define NCODES 1024
#define NROWS 65536

// d_out element offsets (float32)
#define OFF_ZQ   3L
#define OFF_ZOUT 4194307L
#define OFF_PERP 8388611L
#define OFF_ENC  8388612L
#define OFF_IDX  75497476L

#define MARGIN 1e-4f

typedef __attribute__((ext_vector_type(8))) short short8;
typedef __attribute__((ext_vector_type(4))) float f32x4;

static __device__ __forceinline__ unsigned short f2bf_rne(float x) {
    unsigned u = __float_as_uint(x);
    return (unsigned short)((u + 0x7fffu + ((u >> 16) & 1u)) >> 16);
}

// ---------------------------------------------------------------- K0: prep
// Wave per code row (lane = dim). Produces:
//   E_np[j]  : numpy-pairwise fp32 sum of emb[j][:]**2 (scalar r[8] tree)
//   Bp       : pre-fragged bf16 hi/lo MFMA B-operands, per 16-code tile:
//              [beh0(512) | beh1(512) | bel0(512) | bel1(512)] shorts,
//              so k_main's 4 loads per tile are coalesced 1KB each.
//   embT     : dim-major codebook (64 x 1024 fp32) for coalesced k_recheck.
__global__ __launch_bounds__(256) void k_prep(const float* __restrict__ emb,
                                              float* __restrict__ E_np,
                                              short* __restrict__ Bp,
                                              float* __restrict__ embT,
                                              unsigned int* __restrict__ hist,
                                              double* __restrict__ lossAcc,
                                              unsigned int* __restrict__ ambCount,
                                              unsigned int* __restrict__ doneCnt)
{
    const int j = blockIdx.x * 4 + (threadIdx.x >> 6);   // code row, 1024 waves
    const int d = threadIdx.x & 63;                      // dim

    float e = emb[j * DIM + d];
    float s = e * e;
    asm volatile("" : "+v"(s));   // separate rounding (numpy squares first)

    // numpy pairwise n=64: r[t] = a[t] + a[8+t] + ... (left fold), then tree
    float rr[8];
    #pragma unroll
    for (int t = 0; t < 8; ++t) rr[t] = __shfl(s, t, 64);
    #pragma unroll
    for (int i = 1; i < 8; ++i)
        #pragma unroll
        for (int t = 0; t < 8; ++t) rr[t] += __shfl(s, 8 * i + t, 64);
    float En = ((rr[0] + rr[1]) + (rr[2] + rr[3])) + ((rr[4] + rr[5]) + (rr[6] + rr[7]));
    if (d == 0) E_np[j] = En;
    if (d == 1) hist[j] = 0u;

    // bf16 hi/lo split
    unsigned short h = f2bf_rne(e);
    float hf = __uint_as_float(((unsigned)h) << 16);
    unsigned short lo = f2bf_rne(e - hf);

    // scatter into MFMA fragment layout (tile = 16 codes)
    const int t = j >> 4, c = j & 15;
    int pos;
    if (d < 32) pos = t * 2048 + ((d >> 3) * 16 + c) * 8 + (d & 7);
    else        pos = t * 2048 + 512 + (((d - 32) >> 3) * 16 + c) * 8 + ((d - 32) & 7);
    Bp[pos] = (short)h;
    Bp[pos + 1024] = (short)lo;

    embT[d * 1024 + j] = e;

    if (blockIdx.x == 0 && threadIdx.x == 0) {
        *lossAcc = 0.0;
        *ambCount = 0u;
        *doneCnt = 0u;
    }
}

// ------------------------------------------------- K1: MFMA GEMM + top-2
// bf16x3 split GEMM: dot = zh*eh + zl*eh + zh*el (each fp32-accumulated MFMA).
// Wave handles 32 rows x all 1024 codes. B-frags from Bp: coalesced 1KB loads.
// Split error ~1e-6 << MARGIN, so the flag/recheck contract holds.
__global__ __launch_bounds__(256) void k_main(const float* __restrict__ z,
                                              const short* __restrict__ Bp,
                                              const float* __restrict__ E_np,
                                              int* __restrict__ idx,
                                              unsigned int* __restrict__ ambCount,
                                              unsigned int* __restrict__ ambList)
{
    const int lane = threadIdx.x & 63;
    const int l15 = lane & 15;
    const int lHi = lane >> 4;
    const int waveRow = (threadIdx.x >> 6) * 32;
    const long rowBase = (long)blockIdx.x * 128 + waveRow;

    // A-frag layout (16x16x32): row = lane&15, k = (lane>>4)*8 + e.
    short8 ah[4], al[4];
    #pragma unroll
    for (int t = 0; t < 2; ++t) {
        #pragma unroll
        for (int c = 0; c < 2; ++c) {
            const float* zp = z + (rowBase + t * 16 + l15) * DIM + c * 32 + lHi * 8;
            float4 v0 = *(const float4*)zp;
            float4 v1 = *(const float4*)(zp + 4);
            float xs[8] = {v0.x, v0.y, v0.z, v0.w, v1.x, v1.y, v1.z, v1.w};
            short8 hi, lo;
            #pragma unroll
            for (int e = 0; e < 8; ++e) {
                unsigned short h = f2bf_rne(xs[e]);
                float hf = __uint_as_float(((unsigned)h) << 16);
                hi[e] = (short)h;
                lo[e] = (short)f2bf_rne(xs[e] - hf);
            }
            ah[t * 2 + c] = hi;
            al[t * 2 + c] = lo;
        }
    }

    float b1v[8], b2v[8];
    int b1j[8];
    #pragma unroll
    for (int s = 0; s < 8; ++s) { b1v[s] = INFINITY; b2v[s] = INFINITY; b1j[s] = 0; }

    #pragma unroll 1
    for (int tt = 0; tt < 64; ++tt) {              // 64 tiles of 16 codes
        const int code = tt * 16 + l15;            // this lane's B column
        const float e2 = E_np[code];
        const short* base = Bp + (size_t)tt * 2048;
        short8 beh0 = *(const short8*)(base + lane * 8);
        short8 beh1 = *(const short8*)(base + 512 + lane * 8);
        short8 bel0 = *(const short8*)(base + 1024 + lane * 8);
        short8 bel1 = *(const short8*)(base + 1536 + lane * 8);

        #pragma unroll
        for (int t = 0; t < 2; ++t) {
            f32x4 zz = {0.f, 0.f, 0.f, 0.f};
            f32x4 p = __builtin_amdgcn_mfma_f32_16x16x32_bf16(ah[2 * t + 0], beh0, zz, 0, 0, 0);
            p = __builtin_amdgcn_mfma_f32_16x16x32_bf16(al[2 * t + 0], beh0, p, 0, 0, 0);
            p = __builtin_amdgcn_mfma_f32_16x16x32_bf16(ah[2 * t + 0], bel0, p, 0, 0, 0);
            f32x4 q = __builtin_amdgcn_mfma_f32_16x16x32_bf16(ah[2 * t + 1], beh1, zz, 0, 0, 0);
            q = __builtin_amdgcn_mfma_f32_16x16x32_bf16(al[2 * t + 1], beh1, q, 0, 0, 0);
            q = __builtin_amdgcn_mfma_f32_16x16x32_bf16(ah[2 * t + 1], bel1, q, 0, 0, 0);

            #pragma unroll
            for (int r = 0; r < 4; ++r) {
                float dist = fmaf(-2.f, p[r] + q[r], e2);
                int s = t * 4 + r;
                bool lt1 = dist < b1v[s];
                float nb2 = lt1 ? b1v[s] : fminf(b2v[s], dist);
                b1j[s] = lt1 ? code : b1j[s];
                b1v[s] = lt1 ? dist : b1v[s];
                b2v[s] = nb2;
            }
        }
    }

    // merge (best, second) across the 16 lanes of each lHi group
    #pragma unroll
    for (int s = 0; s < 8; ++s) {
        float v1 = b1v[s], v2 = b2v[s];
        int j1 = b1j[s];
        #pragma unroll
        for (int off = 8; off > 0; off >>= 1) {
            float o1 = __shfl_xor(v1, off, 16);
            float o2 = __shfl_xor(v2, off, 16);
            int   oj = __shfl_xor(j1, off, 16);
            bool take = (o1 < v1);
            float n2 = take ? fminf(v1, o2) : fminf(o1, v2);
            if (take) { v1 = o1; j1 = oj; }
            v2 = n2;
        }
        if (l15 == 0) {
            // C/D layout: row = (lane>>4)*4 + reg, col = lane&15
            long row = rowBase + (s >> 2) * 16 + lHi * 4 + (s & 3);
            idx[row] = j1;
            if (v2 - v1 < MARGIN) {
                unsigned int ppos = atomicAdd(ambCount, 1u);
                ambList[ppos] = (unsigned int)row;
            }
        }
    }
}

// -------------------- K2: numpy-fp32 emulated recheck, 4 rows per wave
// embT (dim-major) makes every codebook load a coalesced f32x4 along j:
// lane owns codes j = 4*lane + 256*c + m. Per-row numerics identical:
//   Zf  = numpy pairwise sum (scalar r[8] tree) of fl32(z_d^2)
//   M_j = sequential ascending-k fp32 FMA chain of (2*z_k)*e[j][k]
//   d_j = fl( fl(Zf + E_np[j]) - M_j ), argmin first-index tie-break.
__global__ __launch_bounds__(256) void k_recheck(const float* __restrict__ z,
                                                 const float* __restrict__ embT,
                                                 const float* __restrict__ E_np,
                                                 int* __restrict__ idx,
                                                 const unsigned int* __restrict__ ambCount,
                                                 const unsigned int* __restrict__ ambList)
{
    const int lane = threadIdx.x & 63;
    const unsigned gwave = blockIdx.x * 4 + (threadIdx.x >> 6);
    const unsigned nwaves = gridDim.x * 4;
    const unsigned cnt = *ambCount;
    const unsigned ngroups = (cnt + 3) >> 2;

    for (unsigned w = gwave; w < ngroups; w += nwaves) {
        int rows[4];
        #pragma unroll
        for (int i = 0; i < 4; ++i) {
            unsigned p = w * 4 + (unsigned)i;
            rows[i] = (int)ambList[p < cnt ? p : w * 4];   // tail: duplicate row 0
        }

        float a2v[4], Zfv[4];
        #pragma unroll
        for (int i = 0; i < 4; ++i) {
            float zl = z[(long)rows[i] * DIM + lane];
            float z2 = zl * zl;          // separate rounding (feeds shfl)
            a2v[i] = 2.f * zl;           // exact
            float rr[8];
            #pragma unroll
            for (int t = 0; t < 8; ++t) rr[t] = __shfl(z2, t, 64);
            #pragma unroll
            for (int t = 1; t < 8; ++t)
                #pragma unroll
                for (int u = 0; u < 8; ++u) rr[u] += __shfl(z2, 8 * t + u, 64);
            Zfv[i] = ((rr[0] + rr[1]) + (rr[2] + rr[3])) + ((rr[4] + rr[5]) + (rr[6] + rr[7]));
        }

        float acc[4][4][4];   // [row i][c][m]  for code j = 4*lane + 256*c + m
        #pragma unroll
        for (int i = 0; i < 4; ++i)
            #pragma unroll
            for (int c = 0; c < 4; ++c)
                #pragma unroll
                for (int m = 0; m < 4; ++m) acc[i][c][m] = 0.f;

        #pragma unroll 1
        for (int dq = 0; dq < 16; ++dq) {
            float b[4][4];
            #pragma unroll
            for (int i = 0; i < 4; ++i)
                #pragma unroll
                for (int kk = 0; kk < 4; ++kk)
                    b[i][kk] = __shfl(a2v[i], 4 * dq + kk, 64);
            #pragma unroll
            for (int c = 0; c < 4; ++c) {
                #pragma unroll
                for (int kk = 0; kk < 4; ++kk) {   // k = 4*dq+kk ascending
                    const f32x4 e4 = *(const f32x4*)(embT + (4 * dq + kk) * 1024 + 4 * lane + 256 * c);
                    #pragma unroll
                    for (int i = 0; i < 4; ++i)
                        #pragma unroll
                        for (int m = 0; m < 4; ++m)
                            acc[i][c][m] = fmaf(b[i][kk], e4[m], acc[i][c][m]);
                }
            }
        }

        float bv[4];
        int bj[4];
        #pragma unroll
        for (int i = 0; i < 4; ++i) { bv[i] = INFINITY; bj[i] = 1 << 29; }

        #pragma unroll
        for (int c = 0; c < 4; ++c) {
            const f32x4 En4 = *(const f32x4*)(E_np + 4 * lane + 256 * c);
            #pragma unroll
            for (int m = 0; m < 4; ++m) {
                int j = 4 * lane + 256 * c + m;
                #pragma unroll
                for (int i = 0; i < 4; ++i) {
                    float dd = (Zfv[i] + En4[m]) - acc[i][c][m];   // two separate roundings
                    if (dd < bv[i] || (dd == bv[i] && j < bj[i])) { bv[i] = dd; bj[i] = j; }
                }
            }
        }

        #pragma unroll
        for (int i = 0; i < 4; ++i) {
            float v = bv[i];
            int j = bj[i];
            #pragma unroll
            for (int off = 32; off > 0; off >>= 1) {
                float ov = __shfl_xor(v, off, 64);
                int   oj = __shfl_xor(j, off, 64);
                if (ov < v || (ov == v && oj < j)) { v = ov; j = oj; }
            }
            if (lane == 0) idx[rows[i]] = j;
        }
    }
}

// ------------- K3: fused outputs — one-hot (268 MB) + gather/loss/hist
//                   + fused finalize (last block via device-scope done-counter)
// Phase A is BLOCK-CHUNKED: block b owns rows [32b, 32b+32) as one contiguous
// 128 KB span (long sequential per-channel bursts on the uncached write path),
// 4-row unrolled. One 256-thread f32x4 sweep == exactly one 4 KB one-hot row.
__global__ __launch_bounds__(256) void k_out(const float* __restrict__ z,
                                             const float* __restrict__ emb,
                                             const int* __restrict__ idx,
                                             float* __restrict__ out,
                                             unsigned int* __restrict__ hist,
                                             double* __restrict__ lossAcc,
                                             unsigned int* __restrict__ doneCnt)
{
    // phase A: one-hot, plain f32x4 stores (zeros AND the 1.0, one pass)
    {
        const int r0 = blockIdx.x * 32;               // 2048 blocks x 32 rows
        const int j0 = threadIdx.x * 4;               // this thread's 4 columns
        f32x4* rowp = (f32x4*)(out + OFF_ENC + (long)r0 * NCODES) + threadIdx.x;
        #pragma unroll 1
        for (int rr = 0; rr < 32; rr += 4) {
            int i0 = idx[r0 + rr + 0];
            int i1 = idx[r0 + rr + 1];
            int i2 = idx[r0 + rr + 2];
            int i3 = idx[r0 + rr + 3];
            f32x4 o0, o1, o2, o3;
            #pragma unroll
            for (int m = 0; m < 4; ++m) {
                o0[m] = (j0 + m == i0) ? 1.f : 0.f;
                o1[m] = (j0 + m == i1) ? 1.f : 0.f;
                o2[m] = (j0 + m == i2) ? 1.f : 0.f;
                o3[m] = (j0 + m == i3) ? 1.f : 0.f;
            }
            rowp[(long)(rr + 0) * 256] = o0;
            rowp[(long)(rr + 1) * 256] = o1;
            rowp[(long)(rr + 2) * 256] = o2;
            rowp[(long)(rr + 3) * 256] = o3;
        }
    }

    // phase B: z_q gather, straight-through outputs, loss partial, hist, idx
    __shared__ double red[256];
    __shared__ int lastFlag;
    double part = 0.0;
    const long totalB = (long)NROWS * (DIM / 4);      // 1,048,576 float4
    for (long g4 = (long)blockIdx.x * 256 + threadIdx.x; g4 < totalB;
         g4 += (long)gridDim.x * 256) {
        int r = (int)(g4 >> 4);
        int d0 = ((int)g4 & 15) * 4;
        int i = idx[r];
        float4 e = *(const float4*)(emb + i * DIM + d0);
        float4 zv = *(const float4*)(z + g4 * 4);
        float tx = e.x - zv.x, ty = e.y - zv.y, tz = e.z - zv.z, tw = e.w - zv.w;
        f32x4 zq = {zv.x + tx, zv.y + ty, zv.z + tz, zv.w + tw};
        *(f32x4*)(out + OFF_ZQ + g4 * 4) = zq;
        *(f32x4*)(out + OFF_ZOUT + g4 * 4) = zq;
        part = fma((double)tx, (double)tx, part);
        part = fma((double)ty, (double)ty, part);
        part = fma((double)tz, (double)tz, part);
        part = fma((double)tw, (double)tw, part);
        if (d0 == 0) {
            atomicAdd(&hist[i], 1u);
            out[OFF_IDX + r] = (float)i;
        }
    }
    red[threadIdx.x] = part;
    __syncthreads();
    for (int s = 128; s > 0; s >>= 1) {
        if (threadIdx.x < s) red[threadIdx.x] += red[threadIdx.x + s];
        __syncthreads();
    }
    if (threadIdx.x == 0) {
        atomicAdd(lossAcc, red[0]);
        __threadfence();
        unsigned v = atomicAdd(doneCnt, 1u);
        lastFlag = (v == (unsigned)(gridDim.x - 1)) ? 1 : 0;
    }
    __syncthreads();
    if (lastFlag) {
        __threadfence();   // acquire: see all blocks' hist/lossAcc updates
        double p2 = 0.0;
        for (int b = threadIdx.x; b < NCODES; b += 256) {
            double em = (double)hist[b] * (1.0 / 65536.0);
            p2 += em * log(em + 1e-10);
        }
        red[threadIdx.x] = p2;
        __syncthreads();
        for (int s = 128; s > 0; s >>= 1) {
            if (threadIdx.x < s) red[threadIdx.x] += red[threadIdx.x + s];
            __syncthreads();
        }
        if (threadIdx.x == 0) {
            double H = -red[0];
            double perp = exp(H);
            double m = *lossAcc * (1.0 / 4194304.0);
            out[0] = (float)(m + 0.25 * m);
            out[1] = (float)m;
            out[2] = (float)m;
            out[OFF_PERP] = (float)perp;
        }
    }
}

// --------------------------------------------------------------- launcher
extern "C" void kernel_launch(void* const* d_in, const int* in_sizes, int n_in,
                              void* d_out, int out_size, void* d_ws, size_t ws_size,
                              hipStream_t stream)
{
    const float* z   = (const float*)d_in[0];   // (8192, 512) fp32
    const float* emb = (const float*)d_in[1];   // (1024, 64) fp32
    float* out = (float*)d_out;
    char* ws = (char*)d_ws;

    int*          idx      = (int*)(ws + 0);                 // 65536 * 4
    unsigned int* hist     = (unsigned int*)(ws + 262144);   // 1024 * 4
    double*       lossAcc  = (double*)(ws + 266240);         // 8
    float*        E_np     = (float*)(ws + 266752);          // 1024 * 4
    unsigned int* ambCount = (unsigned int*)(ws + 270848);   // 4
    unsigned int* ambList  = (unsigned int*)(ws + 270852);   // 65536 * 4
    unsigned int* doneCnt  = (unsigned int*)(ws + 532996);   // 4

    // Scratch staged in the one-hot output region (written by k_prep, read by
    // k_main/k_recheck, fully overwritten by k_out phase A — strictly
    // stream-ordered). Round-0/3-proven placement.
    float* scratch = out + OFF_ENC;
    short* Bp   = (short*)scratch;          // 256 KB pre-fragged bf16 hi/lo
    float* embT = scratch + 65536;          // 256 KB dim-major codebook

    hipLaunchKernelGGL(k_prep,    dim3(256),  dim3(256), 0, stream, emb, E_np, Bp, embT, hist, lossAcc, ambCount, doneCnt);
    hipLaunchKernelGGL(k_main,    dim3(512),  dim3(256), 0, stream, z, Bp, E_np, idx, ambCount, ambList);
    hipLaunchKernelGGL(k_recheck, dim3(256),  dim3(256), 0, stream, z, embT, E_np, idx, ambCount, ambList);
    hipLaunchKernelGGL(k_out,     dim3(2048), dim3(256), 0, stream, z, emb, idx, out, hist, lossAcc, doneCnt);
}

// Round 7
// 196.223 us; speedup vs baseline: 1.4920x; 1.4920x over previous
//
#include <hip/hip_runtime.h>
#include <math.h>

#define DIM 64
#define NCODES 1024
#define NROWS 65536

// d_out element offsets (float32)
#define OFF_ZQ   3L
#define OFF_ZOUT 4194307L
#define OFF_PERP 8388611L
#define OFF_ENC  8388612L
#define OFF_IDX  75497476L

#define MARGIN 1e-4f

typedef __attribute__((ext_vector_type(8))) short short8;
typedef __attribute__((ext_vector_type(4))) float f32x4;

static __device__ __forceinline__ unsigned short f2bf_rne(float x) {
    unsigned u = __float_as_uint(x);
    return (unsigned short)((u + 0x7fffu + ((u >> 16) & 1u)) >> 16);
}

// ---------------------------------------------------------------- K0: prep
// Wave per code row (lane = dim). Produces:
//   E_np[j]  : numpy-pairwise fp32 sum of emb[j][:]**2 (scalar r[8] tree)
//   Bp       : pre-fragged bf16 hi/lo MFMA B-operands, per 16-code tile:
//              [beh0(512) | beh1(512) | bel0(512) | bel1(512)] shorts,
//              so k_main's 4 loads per tile are coalesced 1KB each.
//   embT     : dim-major codebook (64 x 1024 fp32) for coalesced k_recheck.
__global__ __launch_bounds__(256) void k_prep(const float* __restrict__ emb,
                                              float* __restrict__ E_np,
                                              short* __restrict__ Bp,
                                              float* __restrict__ embT,
                                              unsigned int* __restrict__ hist,
                                              double* __restrict__ lossAcc,
                                              unsigned int* __restrict__ ambCount)
{
    const int j = blockIdx.x * 4 + (threadIdx.x >> 6);   // code row, 1024 waves
    const int d = threadIdx.x & 63;                      // dim

    float e = emb[j * DIM + d];
    float s = e * e;
    asm volatile("" : "+v"(s));   // separate rounding (numpy squares first)

    // numpy pairwise n=64: r[t] = a[t] + a[8+t] + ... (left fold), then tree
    float rr[8];
    #pragma unroll
    for (int t = 0; t < 8; ++t) rr[t] = __shfl(s, t, 64);
    #pragma unroll
    for (int i = 1; i < 8; ++i)
        #pragma unroll
        for (int t = 0; t < 8; ++t) rr[t] += __shfl(s, 8 * i + t, 64);
    float En = ((rr[0] + rr[1]) + (rr[2] + rr[3])) + ((rr[4] + rr[5]) + (rr[6] + rr[7]));
    if (d == 0) E_np[j] = En;
    if (d == 1) hist[j] = 0u;

    // bf16 hi/lo split
    unsigned short h = f2bf_rne(e);
    float hf = __uint_as_float(((unsigned)h) << 16);
    unsigned short lo = f2bf_rne(e - hf);

    // scatter into MFMA fragment layout (tile = 16 codes)
    const int t = j >> 4, c = j & 15;
    int pos;
    if (d < 32) pos = t * 2048 + ((d >> 3) * 16 + c) * 8 + (d & 7);
    else        pos = t * 2048 + 512 + (((d - 32) >> 3) * 16 + c) * 8 + ((d - 32) & 7);
    Bp[pos] = (short)h;
    Bp[pos + 1024] = (short)lo;

    embT[d * 1024 + j] = e;

    if (blockIdx.x == 0 && threadIdx.x == 0) { *lossAcc = 0.0; *ambCount = 0u; }
}

// ------------------------------------------------- K1: MFMA GEMM + top-2
// bf16x3 split GEMM: dot = zh*eh + zl*eh + zh*el (each fp32-accumulated MFMA).
// Wave handles 32 rows x all 1024 codes. B-frags from Bp: coalesced 1KB loads.
// Split error ~1e-6 << MARGIN, so the flag/recheck contract holds.
__global__ __launch_bounds__(256) void k_main(const float* __restrict__ z,
                                              const short* __restrict__ Bp,
                                              const float* __restrict__ E_np,
                                              int* __restrict__ idx,
                                              unsigned int* __restrict__ ambCount,
                                              unsigned int* __restrict__ ambList)
{
    const int lane = threadIdx.x & 63;
    const int l15 = lane & 15;
    const int lHi = lane >> 4;
    const int waveRow = (threadIdx.x >> 6) * 32;
    const long rowBase = (long)blockIdx.x * 128 + waveRow;

    // A-frag layout (16x16x32): row = lane&15, k = (lane>>4)*8 + e.
    short8 ah[4], al[4];
    #pragma unroll
    for (int t = 0; t < 2; ++t) {
        #pragma unroll
        for (int c = 0; c < 2; ++c) {
            const float* zp = z + (rowBase + t * 16 + l15) * DIM + c * 32 + lHi * 8;
            float4 v0 = *(const float4*)zp;
            float4 v1 = *(const float4*)(zp + 4);
            float xs[8] = {v0.x, v0.y, v0.z, v0.w, v1.x, v1.y, v1.z, v1.w};
            short8 hi, lo;
            #pragma unroll
            for (int e = 0; e < 8; ++e) {
                unsigned short h = f2bf_rne(xs[e]);
                float hf = __uint_as_float(((unsigned)h) << 16);
                hi[e] = (short)h;
                lo[e] = (short)f2bf_rne(xs[e] - hf);
            }
            ah[t * 2 + c] = hi;
            al[t * 2 + c] = lo;
        }
    }

    float b1v[8], b2v[8];
    int b1j[8];
    #pragma unroll
    for (int s = 0; s < 8; ++s) { b1v[s] = INFINITY; b2v[s] = INFINITY; b1j[s] = 0; }

    #pragma unroll 1
    for (int tt = 0; tt < 64; ++tt) {              // 64 tiles of 16 codes
        const int code = tt * 16 + l15;            // this lane's B column
        const float e2 = E_np[code];
        const short* base = Bp + (size_t)tt * 2048;
        short8 beh0 = *(const short8*)(base + lane * 8);
        short8 beh1 = *(const short8*)(base + 512 + lane * 8);
        short8 bel0 = *(const short8*)(base + 1024 + lane * 8);
        short8 bel1 = *(const short8*)(base + 1536 + lane * 8);

        #pragma unroll
        for (int t = 0; t < 2; ++t) {
            f32x4 zz = {0.f, 0.f, 0.f, 0.f};
            f32x4 p = __builtin_amdgcn_mfma_f32_16x16x32_bf16(ah[2 * t + 0], beh0, zz, 0, 0, 0);
            p = __builtin_amdgcn_mfma_f32_16x16x32_bf16(al[2 * t + 0], beh0, p, 0, 0, 0);
            p = __builtin_amdgcn_mfma_f32_16x16x32_bf16(ah[2 * t + 0], bel0, p, 0, 0, 0);
            f32x4 q = __builtin_amdgcn_mfma_f32_16x16x32_bf16(ah[2 * t + 1], beh1, zz, 0, 0, 0);
            q = __builtin_amdgcn_mfma_f32_16x16x32_bf16(al[2 * t + 1], beh1, q, 0, 0, 0);
            q = __builtin_amdgcn_mfma_f32_16x16x32_bf16(ah[2 * t + 1], bel1, q, 0, 0, 0);

            #pragma unroll
            for (int r = 0; r < 4; ++r) {
                float dist = fmaf(-2.f, p[r] + q[r], e2);
                int s = t * 4 + r;
                bool lt1 = dist < b1v[s];
                float nb2 = lt1 ? b1v[s] : fminf(b2v[s], dist);
                b1j[s] = lt1 ? code : b1j[s];
                b1v[s] = lt1 ? dist : b1v[s];
                b2v[s] = nb2;
            }
        }
    }

    // merge (best, second) across the 16 lanes of each lHi group
    #pragma unroll
    for (int s = 0; s < 8; ++s) {
        float v1 = b1v[s], v2 = b2v[s];
        int j1 = b1j[s];
        #pragma unroll
        for (int off = 8; off > 0; off >>= 1) {
            float o1 = __shfl_xor(v1, off, 16);
            float o2 = __shfl_xor(v2, off, 16);
            int   oj = __shfl_xor(j1, off, 16);
            bool take = (o1 < v1);
            float n2 = take ? fminf(v1, o2) : fminf(o1, v2);
            if (take) { v1 = o1; j1 = oj; }
            v2 = n2;
        }
        if (l15 == 0) {
            // C/D layout: row = (lane>>4)*4 + reg, col = lane&15
            long row = rowBase + (s >> 2) * 16 + lHi * 4 + (s & 3);
            idx[row] = j1;
            if (v2 - v1 < MARGIN) {
                unsigned int ppos = atomicAdd(ambCount, 1u);
                ambList[ppos] = (unsigned int)row;
            }
        }
    }
}

// -------------------- K2: numpy-fp32 emulated recheck, 4 rows per wave
// embT (dim-major) makes every codebook load a coalesced f32x4 along j:
// lane owns codes j = 4*lane + 256*c + m. Per-row numerics identical:
//   Zf  = numpy pairwise sum (scalar r[8] tree) of fl32(z_d^2)
//   M_j = sequential ascending-k fp32 FMA chain of (2*z_k)*e[j][k]
//   d_j = fl( fl(Zf + E_np[j]) - M_j ), argmin first-index tie-break.
__global__ __launch_bounds__(256) void k_recheck(const float* __restrict__ z,
                                                 const float* __restrict__ embT,
                                                 const float* __restrict__ E_np,
                                                 int* __restrict__ idx,
                                                 const unsigned int* __restrict__ ambCount,
                                                 const unsigned int* __restrict__ ambList)
{
    const int lane = threadIdx.x & 63;
    const unsigned gwave = blockIdx.x * 4 + (threadIdx.x >> 6);
    const unsigned nwaves = gridDim.x * 4;
    const unsigned cnt = *ambCount;
    const unsigned ngroups = (cnt + 3) >> 2;

    for (unsigned w = gwave; w < ngroups; w += nwaves) {
        int rows[4];
        #pragma unroll
        for (int i = 0; i < 4; ++i) {
            unsigned p = w * 4 + (unsigned)i;
            rows[i] = (int)ambList[p < cnt ? p : w * 4];   // tail: duplicate row 0
        }

        float a2v[4], Zfv[4];
        #pragma unroll
        for (int i = 0; i < 4; ++i) {
            float zl = z[(long)rows[i] * DIM + lane];
            float z2 = zl * zl;          // separate rounding (feeds shfl)
            a2v[i] = 2.f * zl;           // exact
            float rr[8];
            #pragma unroll
            for (int t = 0; t < 8; ++t) rr[t] = __shfl(z2, t, 64);
            #pragma unroll
            for (int t = 1; t < 8; ++t)
                #pragma unroll
                for (int u = 0; u < 8; ++u) rr[u] += __shfl(z2, 8 * t + u, 64);
            Zfv[i] = ((rr[0] + rr[1]) + (rr[2] + rr[3])) + ((rr[4] + rr[5]) + (rr[6] + rr[7]));
        }

        float acc[4][4][4];   // [row i][c][m]  for code j = 4*lane + 256*c + m
        #pragma unroll
        for (int i = 0; i < 4; ++i)
            #pragma unroll
            for (int c = 0; c < 4; ++c)
                #pragma unroll
                for (int m = 0; m < 4; ++m) acc[i][c][m] = 0.f;

        #pragma unroll 1
        for (int dq = 0; dq < 16; ++dq) {
            float b[4][4];
            #pragma unroll
            for (int i = 0; i < 4; ++i)
                #pragma unroll
                for (int kk = 0; kk < 4; ++kk)
                    b[i][kk] = __shfl(a2v[i], 4 * dq + kk, 64);
            #pragma unroll
            for (int c = 0; c < 4; ++c) {
                #pragma unroll
                for (int kk = 0; kk < 4; ++kk) {   // k = 4*dq+kk ascending
                    const f32x4 e4 = *(const f32x4*)(embT + (4 * dq + kk) * 1024 + 4 * lane + 256 * c);
                    #pragma unroll
                    for (int i = 0; i < 4; ++i)
                        #pragma unroll
                        for (int m = 0; m < 4; ++m)
                            acc[i][c][m] = fmaf(b[i][kk], e4[m], acc[i][c][m]);
                }
            }
        }

        float bv[4];
        int bj[4];
        #pragma unroll
        for (int i = 0; i < 4; ++i) { bv[i] = INFINITY; bj[i] = 1 << 29; }

        #pragma unroll
        for (int c = 0; c < 4; ++c) {
            const f32x4 En4 = *(const f32x4*)(E_np + 4 * lane + 256 * c);
            #pragma unroll
            for (int m = 0; m < 4; ++m) {
                int j = 4 * lane + 256 * c + m;
                #pragma unroll
                for (int i = 0; i < 4; ++i) {
                    float dd = (Zfv[i] + En4[m]) - acc[i][c][m];   // two separate roundings
                    if (dd < bv[i] || (dd == bv[i] && j < bj[i])) { bv[i] = dd; bj[i] = j; }
                }
            }
        }

        #pragma unroll
        for (int i = 0; i < 4; ++i) {
            float v = bv[i];
            int j = bj[i];
            #pragma unroll
            for (int off = 32; off > 0; off >>= 1) {
                float ov = __shfl_xor(v, off, 64);
                int   oj = __shfl_xor(j, off, 64);
                if (ov < v || (ov == v && oj < j)) { v = ov; j = oj; }
            }
            if (lane == 0) idx[rows[i]] = j;
        }
    }
}

// ------------- K3: fused outputs — one-hot (268 MB) + gather/loss/hist
// Stores are PLAIN (cached path), grid-stride interleaved, x4 unrolled:
// the store-pattern sweep (NT 1.9 / plain-interleave 2.15 / pure-fill 2.06 /
// runtime memset 2.15 / block-chunked 1.5 TB/s) showed this is the fastest
// writer on this fine-grained output buffer.
__global__ __launch_bounds__(256) void k_out(const float* __restrict__ z,
                                             const float* __restrict__ emb,
                                             const int* __restrict__ idx,
                                             float* __restrict__ out,
                                             unsigned int* __restrict__ hist,
                                             double* __restrict__ lossAcc)
{
    // phase A: one-hot, plain f32x4 stream (zeros AND the 1.0, one pass)
    f32x4* out_enc = (f32x4*)(out + OFF_ENC);
    const long totalA = (long)NROWS * (NCODES / 4);   // 16,777,216 float4
    const long strideA = (long)gridDim.x * 256;       // 524,288 (32 sweeps)
    for (long v = (long)blockIdx.x * 256 + threadIdx.x; v < totalA;
         v += 4 * strideA) {
        #pragma unroll
        for (int u = 0; u < 4; ++u) {
            long vv = v + (long)u * strideA;
            int r = (int)(vv >> 8);
            int j0 = ((int)vv & 255) * 4;
            int i = idx[r];
            f32x4 o;
            o.x = (j0 == i)     ? 1.f : 0.f;
            o.y = (j0 + 1 == i) ? 1.f : 0.f;
            o.z = (j0 + 2 == i) ? 1.f : 0.f;
            o.w = (j0 + 3 == i) ? 1.f : 0.f;
            out_enc[vv] = o;
        }
    }

    // phase B: z_q gather, straight-through outputs, loss partial, hist, idx
    __shared__ double red[256];
    double part = 0.0;
    const long totalB = (long)NROWS * (DIM / 4);      // 1,048,576 float4
    for (long g4 = (long)blockIdx.x * 256 + threadIdx.x; g4 < totalB;
         g4 += (long)gridDim.x * 256) {
        int r = (int)(g4 >> 4);
        int d0 = ((int)g4 & 15) * 4;
        int i = idx[r];
        float4 e = *(const float4*)(emb + i * DIM + d0);
        float4 zv = *(const float4*)(z + g4 * 4);
        float tx = e.x - zv.x, ty = e.y - zv.y, tz = e.z - zv.z, tw = e.w - zv.w;
        f32x4 zq = {zv.x + tx, zv.y + ty, zv.z + tz, zv.w + tw};
        *(f32x4*)(out + OFF_ZQ + g4 * 4) = zq;
        *(f32x4*)(out + OFF_ZOUT + g4 * 4) = zq;
        part = fma((double)tx, (double)tx, part);
        part = fma((double)ty, (double)ty, part);
        part = fma((double)tz, (double)tz, part);
        part = fma((double)tw, (double)tw, part);
        if (d0 == 0) {
            atomicAdd(&hist[i], 1u);
            out[OFF_IDX + r] = (float)i;
        }
    }
    red[threadIdx.x] = part;
    __syncthreads();
    for (int s = 128; s > 0; s >>= 1) {
        if (threadIdx.x < s) red[threadIdx.x] += red[threadIdx.x + s];
        __syncthreads();
    }
    if (threadIdx.x == 0) atomicAdd(lossAcc, red[0]);
}

// ---------------------------------------------------- K4: scalar finalize
__global__ __launch_bounds__(256) void k_final(const unsigned int* __restrict__ hist,
                                               const double* __restrict__ lossAcc,
                                               float* __restrict__ out)
{
    __shared__ double red[256];
    double part = 0.0;
    for (int b = threadIdx.x; b < NCODES; b += 256) {
        double em = (double)hist[b] * (1.0 / 65536.0);
        part += em * log(em + 1e-10);
    }
    red[threadIdx.x] = part;
    __syncthreads();
    for (int s = 128; s > 0; s >>= 1) {
        if (threadIdx.x < s) red[threadIdx.x] += red[threadIdx.x + s];
        __syncthreads();
    }
    if (threadIdx.x == 0) {
        double H = -red[0];
        double perp = exp(H);
        double m = *lossAcc * (1.0 / 4194304.0);
        out[0] = (float)(m + 0.25 * m);
        out[1] = (float)m;
        out[2] = (float)m;
        out[OFF_PERP] = (float)perp;
    }
}

// --------------------------------------------------------------- launcher
extern "C" void kernel_launch(void* const* d_in, const int* in_sizes, int n_in,
                              void* d_out, int out_size, void* d_ws, size_t ws_size,
                              hipStream_t stream)
{
    const float* z   = (const float*)d_in[0];   // (8192, 512) fp32
    const float* emb = (const float*)d_in[1];   // (1024, 64) fp32
    float* out = (float*)d_out;
    char* ws = (char*)d_ws;

    int*          idx      = (int*)(ws + 0);                 // 65536 * 4
    unsigned int* hist     = (unsigned int*)(ws + 262144);   // 1024 * 4
    double*       lossAcc  = (double*)(ws + 266240);         // 8
    float*        E_np     = (float*)(ws + 266752);          // 1024 * 4
    unsigned int* ambCount = (unsigned int*)(ws + 270848);   // 4
    unsigned int* ambList  = (unsigned int*)(ws + 270852);   // 65536 * 4

    // Scratch staged in the one-hot output region (written by k_prep, read by
    // k_main/k_recheck, fully overwritten by k_out phase A — strictly
    // stream-ordered). Round-0/3-proven placement.
    float* scratch = out + OFF_ENC;
    short* Bp   = (short*)scratch;          // 256 KB pre-fragged bf16 hi/lo
    float* embT = scratch + 65536;          // 256 KB dim-major codebook

    hipLaunchKernelGGL(k_prep,    dim3(256),  dim3(256), 0, stream, emb, E_np, Bp, embT, hist, lossAcc, ambCount);
    hipLaunchKernelGGL(k_main,    dim3(512),  dim3(256), 0, stream, z, Bp, E_np, idx, ambCount, ambList);
    hipLaunchKernelGGL(k_recheck, dim3(256),  dim3(256), 0, stream, z, embT, E_np, idx, ambCount, ambList);
    hipLaunchKernelGGL(k_out,     dim3(2048), dim3(256), 0, stream, z, emb, idx, out, hist, lossAcc);
    hipLaunchKernelGGL(k_final,   dim3(1),    dim3(256), 0, stream, hist, lossAcc, out);
}